// Round 1
// baseline (1135.483 us; speedup 1.0000x reference)
//
#include <hip/hip_runtime.h>
#include <hip/hip_bf16.h>
#include <cstdint>

// Problem constants
// B=16, H=W=64, C=512, NH=16, WS=8, SS=4, P=4, HID=2048, N=64, HD=32
// Bw = 1024 windows, tokens = 65536

typedef __attribute__((ext_vector_type(8))) short short8;
typedef __attribute__((ext_vector_type(4))) float f32x4;
typedef unsigned short u16;

__device__ __forceinline__ u16 f2bf(float f) {
  __hip_bfloat16 h = __float2bfloat16(f);
  return *reinterpret_cast<u16*>(&h);
}

__device__ __forceinline__ void gld_lds16(const u16* g, u16* l) {
  __builtin_amdgcn_global_load_lds(
      (const __attribute__((address_space(1))) void*)g,
      (__attribute__((address_space(3))) void*)l, 16, 0, 0);
}

// ---------------------------------------------------------------------------
// Weight convert + transpose: W [K,N] fp32 -> Wt [N,K] bf16
// ---------------------------------------------------------------------------
__global__ void wt_convert(const float* __restrict__ W, u16* __restrict__ Wt,
                           int K, int N) {
  __shared__ float tile[32][33];
  const int n0 = blockIdx.x * 32, k0 = blockIdx.y * 32;
  const int tx = threadIdx.x & 31, ty = threadIdx.x >> 5;  // 32 x 8
#pragma unroll
  for (int r = ty; r < 32; r += 8)
    tile[r][tx] = W[(size_t)(k0 + r) * N + n0 + tx];
  __syncthreads();
#pragma unroll
  for (int r = ty; r < 32; r += 8)
    Wt[(size_t)(n0 + r) * K + k0 + tx] = f2bf(tile[tx][r]);
}

// ---------------------------------------------------------------------------
// A_phi precompute: [NH=16][n=64][m=64] fp32
// ---------------------------------------------------------------------------
__global__ void aphi_kernel(const float* __restrict__ a_p,
                            const float* __restrict__ b_p,
                            float* __restrict__ aphi) {
  const int idx = blockIdx.x * 256 + threadIdx.x;  // 65536 total
  const int h = idx >> 12, n = (idx >> 6) & 63, m = idx & 63;
  const float ang = (float)((n & 7) - (m & 7)) * 0.09817477042468103f;  // 2pi/64
  float v = a_p[h];
#pragma unroll
  for (int p = 0; p < 4; ++p) {
    float s, c;
    __sincosf((float)(p + 1) * ang, &s, &c);
    v += (c * a_p[(p + 1) * 16 + h] + s * b_p[p * 16 + h]) * 0.25f;
  }
  aphi[idx] = v;
}

// ---------------------------------------------------------------------------
// LN1 + roll(-4,-4) + window partition -> xw bf16 [65536,512], dw fp32 [65536]
// one wave per output row
// ---------------------------------------------------------------------------
__global__ __launch_bounds__(64) void ln1_win(
    const float* __restrict__ x, const float* __restrict__ D,
    const float* __restrict__ gamma, const float* __restrict__ beta,
    u16* __restrict__ xw, float* __restrict__ dwout) {
  const int r = blockIdx.x;
  const int lane = threadIdx.x;
  const int w = r >> 6, n = r & 63;
  const int bb = w >> 6, nw = w & 63;
  const int wh = nw >> 3, ww = nw & 7;
  const int i = n >> 3, j = n & 7;
  const int sh = (wh * 8 + i + 4) & 63;
  const int sw = (ww * 8 + j + 4) & 63;
  const size_t src = ((size_t)bb * 4096 + sh * 64 + sw) * 512;
  float4 v0 = *(const float4*)(x + src + lane * 8);
  float4 v1 = *(const float4*)(x + src + lane * 8 + 4);
  float vv[8] = {v0.x, v0.y, v0.z, v0.w, v1.x, v1.y, v1.z, v1.w};
  float s = 0.f, s2 = 0.f;
#pragma unroll
  for (int e = 0; e < 8; ++e) { s += vv[e]; s2 += vv[e] * vv[e]; }
#pragma unroll
  for (int off = 32; off > 0; off >>= 1) {
    s += __shfl_xor(s, off);
    s2 += __shfl_xor(s2, off);
  }
  const float mean = s * (1.0f / 512.0f);
  const float var = s2 * (1.0f / 512.0f) - mean * mean;
  const float rstd = rsqrtf(var + 1e-5f);
  const int c0 = lane * 8;
  u16 ob[8];
#pragma unroll
  for (int e = 0; e < 8; ++e)
    ob[e] = f2bf((vv[e] - mean) * rstd * gamma[c0 + e] + beta[c0 + e]);
  *(short8*)(xw + (size_t)r * 512 + c0) = *(short8*)ob;
  if (lane == 0) dwout[r] = D[(size_t)bb * 4096 + sh * 64 + sw];
}

// ---------------------------------------------------------------------------
// LN2 (token order): x2 fp32 -> h2 bf16
// ---------------------------------------------------------------------------
__global__ __launch_bounds__(64) void ln2_kernel(
    const float* __restrict__ xin, const float* __restrict__ gamma,
    const float* __restrict__ beta, u16* __restrict__ h2) {
  const int r = blockIdx.x;
  const int lane = threadIdx.x;
  const size_t src = (size_t)r * 512;
  float4 v0 = *(const float4*)(xin + src + lane * 8);
  float4 v1 = *(const float4*)(xin + src + lane * 8 + 4);
  float vv[8] = {v0.x, v0.y, v0.z, v0.w, v1.x, v1.y, v1.z, v1.w};
  float s = 0.f, s2 = 0.f;
#pragma unroll
  for (int e = 0; e < 8; ++e) { s += vv[e]; s2 += vv[e] * vv[e]; }
#pragma unroll
  for (int off = 32; off > 0; off >>= 1) {
    s += __shfl_xor(s, off);
    s2 += __shfl_xor(s2, off);
  }
  const float mean = s * (1.0f / 512.0f);
  const float var = s2 * (1.0f / 512.0f) - mean * mean;
  const float rstd = rsqrtf(var + 1e-5f);
  const int c0 = lane * 8;
  u16 ob[8];
#pragma unroll
  for (int e = 0; e < 8; ++e)
    ob[e] = f2bf((vv[e] - mean) * rstd * gamma[c0 + e] + beta[c0 + e]);
  *(short8*)(h2 + src + c0) = *(short8*)ob;
}

// ---------------------------------------------------------------------------
// bf16 GEMM, C[M,N] = A[M,K] * Bt[N,K]^T (+bias, +epilogue)
// 128x128 tile, BK=32, 4 waves (2x2), 16x16x32 mfma, global_load_lds staging,
// XOR chunk swizzle -> 2-way (free) LDS bank pattern on ds_read_b128.
// EPI: 0 = bias->bf16; 1 = bias+gelu->bf16;
//      2 = bias + unwindow/unroll + residual(x) -> fp32 d_out;
//      3 = bias + accumulate into fp32 d_out (token order)
// ---------------------------------------------------------------------------
template <int EPI>
__global__ __launch_bounds__(256, 2) void gemm_bt(
    const u16* __restrict__ A, const u16* __restrict__ Bt,
    const float* __restrict__ bias, u16* __restrict__ outb,
    float* __restrict__ outf, const float* __restrict__ addsrc,
    int M, int N, int K) {
  __shared__ __align__(16) u16 sA[128 * 32];
  __shared__ __align__(16) u16 sB[128 * 32];
  const int t = threadIdx.x;
  const int m0 = blockIdx.y * 128, n0 = blockIdx.x * 128;
  const int lane = t & 63, wave = t >> 6;
  const int wm = wave >> 1, wn = wave & 1;
  const int l15 = lane & 15, quad = lane >> 4;

  f32x4 acc[4][4];
#pragma unroll
  for (int i = 0; i < 4; ++i)
#pragma unroll
    for (int j = 0; j < 4; ++j) acc[i][j] = (f32x4){0.f, 0.f, 0.f, 0.f};

  const int r0 = t >> 2, cs = t & 3;
  const int r1 = r0 + 64;
  const int gc0 = cs ^ ((r0 >> 1) & 3);
  const int gc1 = cs ^ ((r1 >> 1) & 3);
  const u16* Ag0 = A + (size_t)(m0 + r0) * K + gc0 * 8;
  const u16* Ag1 = A + (size_t)(m0 + r1) * K + gc1 * 8;
  const u16* Bg0 = Bt + (size_t)(n0 + r0) * K + gc0 * 8;
  const u16* Bg1 = Bt + (size_t)(n0 + r1) * K + gc1 * 8;
  u16* lA0 = &sA[t * 8];
  u16* lA1 = &sA[2048 + t * 8];
  u16* lB0 = &sB[t * 8];
  u16* lB1 = &sB[2048 + t * 8];

  for (int kk = 0; kk < K; kk += 32) {
    gld_lds16(Ag0 + kk, lA0);
    gld_lds16(Ag1 + kk, lA1);
    gld_lds16(Bg0 + kk, lB0);
    gld_lds16(Bg1 + kk, lB1);
    __syncthreads();
    short8 af[4], bf[4];
#pragma unroll
    for (int i = 0; i < 4; ++i) {
      const int ra = wm * 64 + i * 16 + l15;
      const int ca = quad ^ ((ra >> 1) & 3);
      af[i] = *(const short8*)&sA[ra * 32 + ca * 8];
      const int rb = wn * 64 + i * 16 + l15;
      const int cb = quad ^ ((rb >> 1) & 3);
      bf[i] = *(const short8*)&sB[rb * 32 + cb * 8];
    }
#pragma unroll
    for (int i = 0; i < 4; ++i)
#pragma unroll
      for (int j = 0; j < 4; ++j)
        acc[i][j] = __builtin_amdgcn_mfma_f32_16x16x32_bf16(af[i], bf[j],
                                                            acc[i][j], 0, 0, 0);
    __syncthreads();
  }

#pragma unroll
  for (int i = 0; i < 4; ++i) {
    const int gr0 = m0 + wm * 64 + i * 16 + quad * 4;
#pragma unroll
    for (int j = 0; j < 4; ++j) {
      const int gc = n0 + wn * 64 + j * 16 + l15;
      const float bv = bias[gc];
      f32x4 a = acc[i][j];
#pragma unroll
      for (int r = 0; r < 4; ++r) {
        const int gr = gr0 + r;
        float val = a[r] + bv;
        if (EPI == 0) {
          outb[(size_t)gr * N + gc] = f2bf(val);
        } else if (EPI == 1) {
          val = 0.5f * val * (1.0f + erff(val * 0.7071067811865475f));
          outb[(size_t)gr * N + gc] = f2bf(val);
        } else if (EPI == 2) {
          const int w = gr >> 6, n = gr & 63;
          const int bb = w >> 6, nw = w & 63;
          const int wh = nw >> 3, ww = nw & 7;
          const int ii = n >> 3, jj = n & 7;
          const int th = (wh * 8 + ii + 4) & 63;
          const int tw = (ww * 8 + jj + 4) & 63;
          const size_t tok = (size_t)bb * 4096 + th * 64 + tw;
          outf[tok * 512 + gc] = addsrc[tok * 512 + gc] + val;
        } else {
          outf[(size_t)gr * N + gc] += val;
        }
      }
    }
  }
}

// ---------------------------------------------------------------------------
// Fused windowed attention, one wave per (window, head).
// S = QK^T*scale + A_phi + A_r(trig recurrence) + shift-mask; in-register
// softmax (16-lane shuffles); P -> LDS -> A-frag; O = P V via mfma.
// ---------------------------------------------------------------------------
__device__ __forceinline__ int bandf(int p) {
  return p < 56 ? 0 : (p < 60 ? 1 : 2);
}

__global__ void attn_kernel(const u16* __restrict__ qkv,
                            const float* __restrict__ dw,
                            const float* __restrict__ aphi,
                            const float* __restrict__ a_r,
                            const float* __restrict__ b_r,
                            u16* __restrict__ outp) {
  __shared__ __align__(16) u16 sVt[32 * 72];
  __shared__ __align__(16) u16 sP[64 * 72];
  __shared__ float sdw[64];
  const int bid = blockIdx.x;
  const int w = bid >> 4, h = bid & 15;
  const int lane = threadIdx.x;
  const int l15 = lane & 15, quad = lane >> 4;
  const int nw = w & 63, wh = nw >> 3, wwc = nw & 7;

  const float ar0 = a_r[h];
  float arc[4], brc[4];
#pragma unroll
  for (int p = 0; p < 4; ++p) {
    arc[p] = a_r[(p + 1) * 16 + h] * 0.25f;
    brc[p] = b_r[p * 16 + h] * 0.25f;
  }

  sdw[lane] = dw[w * 64 + lane];
  {
    const u16* vrow = qkv + (size_t)(w * 64 + lane) * 1536 + 1024 + h * 32;
    u16 vt[32];
#pragma unroll
    for (int c = 0; c < 4; ++c)
      *(short8*)&vt[c * 8] = *(const short8*)(vrow + c * 8);
#pragma unroll
    for (int d = 0; d < 32; ++d) sVt[d * 72 + lane] = vt[d];
  }
  __syncthreads();

  short8 qf[4], kf[4];
#pragma unroll
  for (int tq = 0; tq < 4; ++tq) {
    qf[tq] = *(const short8*)(qkv + (size_t)(w * 64 + tq * 16 + l15) * 1536 +
                              h * 32 + quad * 8);
    kf[tq] = *(const short8*)(qkv + (size_t)(w * 64 + tq * 16 + l15) * 1536 +
                              512 + h * 32 + quad * 8);
  }

  float dn[16];
  int rq[16];
#pragma unroll
  for (int tm = 0; tm < 4; ++tm)
#pragma unroll
    for (int r = 0; r < 4; ++r) {
      const int n = tm * 16 + quad * 4 + r;
      dn[tm * 4 + r] = sdw[n];
      rq[tm * 4 + r] = bandf(wh * 8 + (n >> 3)) * 4 + bandf(wwc * 8 + (n & 7));
    }
  float dmv[4];
  int rk[4];
#pragma unroll
  for (int tn = 0; tn < 4; ++tn) {
    const int m = tn * 16 + l15;
    dmv[tn] = sdw[m];
    rk[tn] = bandf(wh * 8 + (m >> 3)) * 4 + bandf(wwc * 8 + (m & 7));
  }

  f32x4 S[4][4];
  const float SCALE = 0.17677669529663687f;  // 32^-0.5
#pragma unroll
  for (int tm = 0; tm < 4; ++tm)
#pragma unroll
    for (int tn = 0; tn < 4; ++tn) {
      f32x4 s = __builtin_amdgcn_mfma_f32_16x16x32_bf16(
          qf[tm], kf[tn], (f32x4){0.f, 0.f, 0.f, 0.f}, 0, 0, 0);
      const int m = tn * 16 + l15;
#pragma unroll
      for (int r = 0; r < 4; ++r) {
        const int n = tm * 16 + quad * 4 + r;
        const float rad = dmv[tn] - dn[tm * 4 + r];
        float s1, c1;
        __sincosf(3.14159265358979323846f * rad, &s1, &c1);
        const float c2 = c1 * c1 - s1 * s1, t2 = 2.f * s1 * c1;
        const float c3 = c2 * c1 - t2 * s1, t3 = t2 * c1 + c2 * s1;
        const float c4 = c2 * c2 - t2 * t2, t4 = 2.f * t2 * c2;
        const float arv = ar0 + c1 * arc[0] + s1 * brc[0] + c2 * arc[1] +
                          t2 * brc[1] + c3 * arc[2] + t3 * brc[2] +
                          c4 * arc[3] + t4 * brc[3];
        float val = s[r] * SCALE + aphi[h * 4096 + n * 64 + m] + arv;
        if (rq[tm * 4 + r] != rk[tn]) val -= 100.f;
        S[tm][tn][r] = val;
      }
    }

#pragma unroll
  for (int tm = 0; tm < 4; ++tm)
#pragma unroll
    for (int r = 0; r < 4; ++r) {
      float mx = fmaxf(fmaxf(S[tm][0][r], S[tm][1][r]),
                       fmaxf(S[tm][2][r], S[tm][3][r]));
#pragma unroll
      for (int off = 1; off < 16; off <<= 1) mx = fmaxf(mx, __shfl_xor(mx, off));
      float sm = 0.f;
#pragma unroll
      for (int tn = 0; tn < 4; ++tn) {
        const float e = __expf(S[tm][tn][r] - mx);
        S[tm][tn][r] = e;
        sm += e;
      }
#pragma unroll
      for (int off = 1; off < 16; off <<= 1) sm += __shfl_xor(sm, off);
      const float inv = 1.0f / sm;
      const int n = tm * 16 + quad * 4 + r;
#pragma unroll
      for (int tn = 0; tn < 4; ++tn)
        sP[n * 72 + tn * 16 + l15] = f2bf(S[tm][tn][r] * inv);
    }
  __syncthreads();

  short8 vf[2][2];
#pragma unroll
  for (int ks = 0; ks < 2; ++ks)
#pragma unroll
    for (int td = 0; td < 2; ++td)
      vf[ks][td] =
          *(const short8*)&sVt[(td * 16 + l15) * 72 + ks * 32 + quad * 8];
  f32x4 O[4][2];
#pragma unroll
  for (int tm = 0; tm < 4; ++tm)
#pragma unroll
    for (int td = 0; td < 2; ++td) O[tm][td] = (f32x4){0.f, 0.f, 0.f, 0.f};
#pragma unroll
  for (int tm = 0; tm < 4; ++tm)
#pragma unroll
    for (int ks = 0; ks < 2; ++ks) {
      const short8 pf =
          *(const short8*)&sP[(tm * 16 + l15) * 72 + ks * 32 + quad * 8];
#pragma unroll
      for (int td = 0; td < 2; ++td)
        O[tm][td] =
            __builtin_amdgcn_mfma_f32_16x16x32_bf16(pf, vf[ks][td], O[tm][td], 0, 0, 0);
    }

#pragma unroll
  for (int tm = 0; tm < 4; ++tm)
#pragma unroll
    for (int td = 0; td < 2; ++td)
#pragma unroll
      for (int r = 0; r < 4; ++r) {
        const int n = tm * 16 + quad * 4 + r;
        const int d = td * 16 + l15;
        outp[(size_t)(w * 64 + n) * 512 + h * 32 + d] = f2bf(O[tm][td][r]);
      }
}

// ---------------------------------------------------------------------------
// Host
// ---------------------------------------------------------------------------
extern "C" void kernel_launch(void* const* d_in, const int* in_sizes, int n_in,
                              void* d_out, int out_size, void* d_ws,
                              size_t ws_size, hipStream_t stream) {
  const float* x = (const float*)d_in[0];
  const float* D = (const float*)d_in[1];
  const float* gamma1 = (const float*)d_in[2];
  const float* beta1 = (const float*)d_in[3];
  const float* Wqkv = (const float*)d_in[4];
  const float* bqkv = (const float*)d_in[5];
  const float* Wproj = (const float*)d_in[6];
  const float* bproj = (const float*)d_in[7];
  const float* a_p = (const float*)d_in[8];
  const float* b_p = (const float*)d_in[9];
  const float* a_r = (const float*)d_in[10];
  const float* b_r = (const float*)d_in[11];
  const float* gamma2 = (const float*)d_in[12];
  const float* beta2 = (const float*)d_in[13];
  const float* W1 = (const float*)d_in[14];
  const float* b1 = (const float*)d_in[15];
  const float* W2 = (const float*)d_in[16];
  const float* b2 = (const float*)d_in[17];
  float* out = (float*)d_out;

  char* ws = (char*)d_ws;
  const size_t OFF_XW = 0;                    // 67,108,864   (xw, later h2)
  const size_t OFF_QKV = 67108864;            // 268,435,456  (qkv, later g)
  const size_t OFF_AO = 335544320;            // 67,108,864   (attn out)
  const size_t OFF_WQT = 402653184;           // 1,572,864
  const size_t OFF_WPT = 404226048;           // 524,288
  const size_t OFF_W1T = 404750336;           // 2,097,152
  const size_t OFF_W2T = 406847488;           // 2,097,152
  const size_t OFF_APHI = 408944640;          // 262,144
  const size_t OFF_DW = 409206784;            // 262,144
  const size_t TOTAL = 409468928;
  if (ws_size < TOTAL) return;

  u16* xw = (u16*)(ws + OFF_XW);
  u16* qkv = (u16*)(ws + OFF_QKV);
  u16* ao = (u16*)(ws + OFF_AO);
  u16* WqkvT = (u16*)(ws + OFF_WQT);
  u16* WprojT = (u16*)(ws + OFF_WPT);
  u16* W1T = (u16*)(ws + OFF_W1T);
  u16* W2T = (u16*)(ws + OFF_W2T);
  float* aphiW = (float*)(ws + OFF_APHI);
  float* dwW = (float*)(ws + OFF_DW);
  u16* h2 = xw;   // reuse
  u16* gbuf = qkv;  // reuse

  wt_convert<<<dim3(48, 16), 256, 0, stream>>>(Wqkv, WqkvT, 512, 1536);
  wt_convert<<<dim3(16, 16), 256, 0, stream>>>(Wproj, WprojT, 512, 512);
  wt_convert<<<dim3(64, 16), 256, 0, stream>>>(W1, W1T, 512, 2048);
  wt_convert<<<dim3(16, 64), 256, 0, stream>>>(W2, W2T, 2048, 512);
  aphi_kernel<<<256, 256, 0, stream>>>(a_p, b_p, aphiW);
  ln1_win<<<65536, 64, 0, stream>>>(x, D, gamma1, beta1, xw, dwW);

  gemm_bt<0><<<dim3(12, 512), 256, 0, stream>>>(xw, WqkvT, bqkv, qkv, nullptr,
                                                nullptr, 65536, 1536, 512);
  attn_kernel<<<16384, 64, 0, stream>>>(qkv, dwW, aphiW, a_r, b_r, ao);
  gemm_bt<2><<<dim3(4, 512), 256, 0, stream>>>(ao, WprojT, bproj, nullptr, out,
                                               x, 65536, 512, 512);
  ln2_kernel<<<65536, 64, 0, stream>>>(out, gamma2, beta2, h2);
  gemm_bt<1><<<dim3(16, 512), 256, 0, stream>>>(h2, W1T, b1, gbuf, nullptr,
                                                nullptr, 65536, 2048, 512);
  gemm_bt<3><<<dim3(4, 512), 256, 0, stream>>>(gbuf, W2T, b2, nullptr, out,
                                               nullptr, 65536, 512, 2048);
}

// Round 2
// 1113.916 us; speedup vs baseline: 1.0194x; 1.0194x over previous
//
#include <hip/hip_runtime.h>
#include <hip/hip_bf16.h>
#include <cstdint>

// Problem constants
// B=16, H=W=64, C=512, NH=16, WS=8, SS=4, P=4, HID=2048, N=64, HD=32
// Bw = 1024 windows, tokens = 65536

typedef __attribute__((ext_vector_type(8))) short short8;
typedef __attribute__((ext_vector_type(4))) float f32x4;
typedef unsigned short u16;

__device__ __forceinline__ u16 f2bf(float f) {
  __hip_bfloat16 h = __float2bfloat16(f);
  return *reinterpret_cast<u16*>(&h);
}

__device__ __forceinline__ void gld_lds16(const u16* g, u16* l) {
  __builtin_amdgcn_global_load_lds(
      (const __attribute__((address_space(1))) void*)g,
      (__attribute__((address_space(3))) void*)l, 16, 0, 0);
}

// ---------------------------------------------------------------------------
// Weight convert + transpose: W [K,N] fp32 -> Wt [N,K] bf16
// ---------------------------------------------------------------------------
__global__ void wt_convert(const float* __restrict__ W, u16* __restrict__ Wt,
                           int K, int N) {
  __shared__ float tile[32][33];
  const int n0 = blockIdx.x * 32, k0 = blockIdx.y * 32;
  const int tx = threadIdx.x & 31, ty = threadIdx.x >> 5;  // 32 x 8
#pragma unroll
  for (int r = ty; r < 32; r += 8)
    tile[r][tx] = W[(size_t)(k0 + r) * N + n0 + tx];
  __syncthreads();
#pragma unroll
  for (int r = ty; r < 32; r += 8)
    Wt[(size_t)(n0 + r) * K + k0 + tx] = f2bf(tile[tx][r]);
}

// ---------------------------------------------------------------------------
// A_phi precompute: [NH=16][n=64][m=64] fp32
// ---------------------------------------------------------------------------
__global__ void aphi_kernel(const float* __restrict__ a_p,
                            const float* __restrict__ b_p,
                            float* __restrict__ aphi) {
  const int idx = blockIdx.x * 256 + threadIdx.x;  // 65536 total
  const int h = idx >> 12, n = (idx >> 6) & 63, m = idx & 63;
  const float ang = (float)((n & 7) - (m & 7)) * 0.09817477042468103f;  // 2pi/64
  float v = a_p[h];
#pragma unroll
  for (int p = 0; p < 4; ++p) {
    float s, c;
    __sincosf((float)(p + 1) * ang, &s, &c);
    v += (c * a_p[(p + 1) * 16 + h] + s * b_p[p * 16 + h]) * 0.25f;
  }
  aphi[idx] = v;
}

// ---------------------------------------------------------------------------
// LN1 + roll(-4,-4) + window partition -> xw bf16 [65536,512], dw fp32 [65536]
// one wave per output row
// ---------------------------------------------------------------------------
__global__ __launch_bounds__(64) void ln1_win(
    const float* __restrict__ x, const float* __restrict__ D,
    const float* __restrict__ gamma, const float* __restrict__ beta,
    u16* __restrict__ xw, float* __restrict__ dwout) {
  const int r = blockIdx.x;
  const int lane = threadIdx.x;
  const int w = r >> 6, n = r & 63;
  const int bb = w >> 6, nw = w & 63;
  const int wh = nw >> 3, ww = nw & 7;
  const int i = n >> 3, j = n & 7;
  const int sh = (wh * 8 + i + 4) & 63;
  const int sw = (ww * 8 + j + 4) & 63;
  const size_t src = ((size_t)bb * 4096 + sh * 64 + sw) * 512;
  float4 v0 = *(const float4*)(x + src + lane * 8);
  float4 v1 = *(const float4*)(x + src + lane * 8 + 4);
  float vv[8] = {v0.x, v0.y, v0.z, v0.w, v1.x, v1.y, v1.z, v1.w};
  float s = 0.f, s2 = 0.f;
#pragma unroll
  for (int e = 0; e < 8; ++e) { s += vv[e]; s2 += vv[e] * vv[e]; }
#pragma unroll
  for (int off = 32; off > 0; off >>= 1) {
    s += __shfl_xor(s, off);
    s2 += __shfl_xor(s2, off);
  }
  const float mean = s * (1.0f / 512.0f);
  const float var = s2 * (1.0f / 512.0f) - mean * mean;
  const float rstd = rsqrtf(var + 1e-5f);
  const int c0 = lane * 8;
  u16 ob[8];
#pragma unroll
  for (int e = 0; e < 8; ++e)
    ob[e] = f2bf((vv[e] - mean) * rstd * gamma[c0 + e] + beta[c0 + e]);
  *(short8*)(xw + (size_t)r * 512 + c0) = *(short8*)ob;
  if (lane == 0) dwout[r] = D[(size_t)bb * 4096 + sh * 64 + sw];
}

// ---------------------------------------------------------------------------
// LN2 (token order): x2 fp32 -> h2 bf16
// ---------------------------------------------------------------------------
__global__ __launch_bounds__(64) void ln2_kernel(
    const float* __restrict__ xin, const float* __restrict__ gamma,
    const float* __restrict__ beta, u16* __restrict__ h2) {
  const int r = blockIdx.x;
  const int lane = threadIdx.x;
  const size_t src = (size_t)r * 512;
  float4 v0 = *(const float4*)(xin + src + lane * 8);
  float4 v1 = *(const float4*)(xin + src + lane * 8 + 4);
  float vv[8] = {v0.x, v0.y, v0.z, v0.w, v1.x, v1.y, v1.z, v1.w};
  float s = 0.f, s2 = 0.f;
#pragma unroll
  for (int e = 0; e < 8; ++e) { s += vv[e]; s2 += vv[e] * vv[e]; }
#pragma unroll
  for (int off = 32; off > 0; off >>= 1) {
    s += __shfl_xor(s, off);
    s2 += __shfl_xor(s2, off);
  }
  const float mean = s * (1.0f / 512.0f);
  const float var = s2 * (1.0f / 512.0f) - mean * mean;
  const float rstd = rsqrtf(var + 1e-5f);
  const int c0 = lane * 8;
  u16 ob[8];
#pragma unroll
  for (int e = 0; e < 8; ++e)
    ob[e] = f2bf((vv[e] - mean) * rstd * gamma[c0 + e] + beta[c0 + e]);
  *(short8*)(h2 + src + c0) = *(short8*)ob;
}

// ---------------------------------------------------------------------------
// bf16 GEMM, C[M,N] = A[M,K] * Bt[N,K]^T (+bias, +epilogue)
// 128x128 tile, BK=32, 4 waves (2x2), 16x16x32 mfma, global_load_lds staging,
// XOR chunk swizzle -> 2-way (free) LDS bank pattern on ds_read_b128.
// 1D grid + XCD swizzle: lid&7 selects M-stripe so every N-tile of one A
// row-tile lands on the same XCD's L2 (A fetched once per L2, not 8x).
// EPI: 0 = bias->bf16; 1 = bias+gelu->bf16;
//      2 = bias + unwindow/unroll + residual(x) -> fp32 d_out;
//      3 = bias + accumulate into fp32 d_out (token order)
// ---------------------------------------------------------------------------
template <int EPI, int GX>
__global__ __launch_bounds__(256, 4) void gemm_bt(
    const u16* __restrict__ A, const u16* __restrict__ Bt,
    const float* __restrict__ bias, u16* __restrict__ outb,
    float* __restrict__ outf, const float* __restrict__ addsrc,
    int M, int N, int K) {
  __shared__ __align__(16) u16 sA[128 * 32];
  __shared__ __align__(16) u16 sB[128 * 32];
  const int t = threadIdx.x;
  // XCD-locality swizzle: stripe M across XCDs, iterate N fast within XCD.
  const int lid = blockIdx.x;
  const int xcd = lid & 7;
  const int tt = lid >> 3;
  const int bx = tt % GX;
  const int by = (tt / GX) * 8 + xcd;
  const int m0 = by * 128, n0 = bx * 128;
  const int lane = t & 63, wave = t >> 6;
  const int wm = wave >> 1, wn = wave & 1;
  const int l15 = lane & 15, quad = lane >> 4;

  f32x4 acc[4][4];
#pragma unroll
  for (int i = 0; i < 4; ++i)
#pragma unroll
    for (int j = 0; j < 4; ++j) acc[i][j] = (f32x4){0.f, 0.f, 0.f, 0.f};

  const int r0 = t >> 2, cs = t & 3;
  const int r1 = r0 + 64;
  const int gc0 = cs ^ ((r0 >> 1) & 3);
  const int gc1 = cs ^ ((r1 >> 1) & 3);
  const u16* Ag0 = A + (size_t)(m0 + r0) * K + gc0 * 8;
  const u16* Ag1 = A + (size_t)(m0 + r1) * K + gc1 * 8;
  const u16* Bg0 = Bt + (size_t)(n0 + r0) * K + gc0 * 8;
  const u16* Bg1 = Bt + (size_t)(n0 + r1) * K + gc1 * 8;
  u16* lA0 = &sA[t * 8];
  u16* lA1 = &sA[2048 + t * 8];
  u16* lB0 = &sB[t * 8];
  u16* lB1 = &sB[2048 + t * 8];

  for (int kk = 0; kk < K; kk += 32) {
    gld_lds16(Ag0 + kk, lA0);
    gld_lds16(Ag1 + kk, lA1);
    gld_lds16(Bg0 + kk, lB0);
    gld_lds16(Bg1 + kk, lB1);
    __syncthreads();
    short8 af[4], bf[4];
#pragma unroll
    for (int i = 0; i < 4; ++i) {
      const int ra = wm * 64 + i * 16 + l15;
      const int ca = quad ^ ((ra >> 1) & 3);
      af[i] = *(const short8*)&sA[ra * 32 + ca * 8];
      const int rb = wn * 64 + i * 16 + l15;
      const int cb = quad ^ ((rb >> 1) & 3);
      bf[i] = *(const short8*)&sB[rb * 32 + cb * 8];
    }
#pragma unroll
    for (int i = 0; i < 4; ++i)
#pragma unroll
      for (int j = 0; j < 4; ++j)
        acc[i][j] = __builtin_amdgcn_mfma_f32_16x16x32_bf16(af[i], bf[j],
                                                            acc[i][j], 0, 0, 0);
    __syncthreads();
  }

#pragma unroll
  for (int i = 0; i < 4; ++i) {
    const int gr0 = m0 + wm * 64 + i * 16 + quad * 4;
#pragma unroll
    for (int j = 0; j < 4; ++j) {
      const int gc = n0 + wn * 64 + j * 16 + l15;
      const float bv = bias[gc];
      f32x4 a = acc[i][j];
#pragma unroll
      for (int r = 0; r < 4; ++r) {
        const int gr = gr0 + r;
        float val = a[r] + bv;
        if (EPI == 0) {
          outb[(size_t)gr * N + gc] = f2bf(val);
        } else if (EPI == 1) {
          val = 0.5f * val * (1.0f + erff(val * 0.7071067811865475f));
          outb[(size_t)gr * N + gc] = f2bf(val);
        } else if (EPI == 2) {
          const int w = gr >> 6, n = gr & 63;
          const int bb = w >> 6, nw = w & 63;
          const int wh = nw >> 3, ww = nw & 7;
          const int ii = n >> 3, jj = n & 7;
          const int th = (wh * 8 + ii + 4) & 63;
          const int tw = (ww * 8 + jj + 4) & 63;
          const size_t tok = (size_t)bb * 4096 + th * 64 + tw;
          outf[tok * 512 + gc] = addsrc[tok * 512 + gc] + val;
        } else {
          outf[(size_t)gr * N + gc] += val;
        }
      }
    }
  }
}

// ---------------------------------------------------------------------------
// Fused windowed attention, one wave per (window, head).
// S = QK^T*scale + A_phi + A_r(trig recurrence) + shift-mask; in-register
// softmax (16-lane shuffles); P -> LDS -> A-frag; O = P V via mfma.
// ---------------------------------------------------------------------------
__device__ __forceinline__ int bandf(int p) {
  return p < 56 ? 0 : (p < 60 ? 1 : 2);
}

__global__ void attn_kernel(const u16* __restrict__ qkv,
                            const float* __restrict__ dw,
                            const float* __restrict__ aphi,
                            const float* __restrict__ a_r,
                            const float* __restrict__ b_r,
                            u16* __restrict__ outp) {
  __shared__ __align__(16) u16 sVt[32 * 72];
  __shared__ __align__(16) u16 sP[64 * 72];
  __shared__ float sdw[64];
  const int bid = blockIdx.x;
  const int w = bid >> 4, h = bid & 15;
  const int lane = threadIdx.x;
  const int l15 = lane & 15, quad = lane >> 4;
  const int nw = w & 63, wh = nw >> 3, wwc = nw & 7;

  const float ar0 = a_r[h];
  float arc[4], brc[4];
#pragma unroll
  for (int p = 0; p < 4; ++p) {
    arc[p] = a_r[(p + 1) * 16 + h] * 0.25f;
    brc[p] = b_r[p * 16 + h] * 0.25f;
  }

  sdw[lane] = dw[w * 64 + lane];
  {
    const u16* vrow = qkv + (size_t)(w * 64 + lane) * 1536 + 1024 + h * 32;
    u16 vt[32];
#pragma unroll
    for (int c = 0; c < 4; ++c)
      *(short8*)&vt[c * 8] = *(const short8*)(vrow + c * 8);
#pragma unroll
    for (int d = 0; d < 32; ++d) sVt[d * 72 + lane] = vt[d];
  }
  __syncthreads();

  short8 qf[4], kf[4];
#pragma unroll
  for (int tq = 0; tq < 4; ++tq) {
    qf[tq] = *(const short8*)(qkv + (size_t)(w * 64 + tq * 16 + l15) * 1536 +
                              h * 32 + quad * 8);
    kf[tq] = *(const short8*)(qkv + (size_t)(w * 64 + tq * 16 + l15) * 1536 +
                              512 + h * 32 + quad * 8);
  }

  float dn[16];
  int rq[16];
#pragma unroll
  for (int tm = 0; tm < 4; ++tm)
#pragma unroll
    for (int r = 0; r < 4; ++r) {
      const int n = tm * 16 + quad * 4 + r;
      dn[tm * 4 + r] = sdw[n];
      rq[tm * 4 + r] = bandf(wh * 8 + (n >> 3)) * 4 + bandf(wwc * 8 + (n & 7));
    }
  float dmv[4];
  int rk[4];
#pragma unroll
  for (int tn = 0; tn < 4; ++tn) {
    const int m = tn * 16 + l15;
    dmv[tn] = sdw[m];
    rk[tn] = bandf(wh * 8 + (m >> 3)) * 4 + bandf(wwc * 8 + (m & 7));
  }

  f32x4 S[4][4];
  const float SCALE = 0.17677669529663687f;  // 32^-0.5
#pragma unroll
  for (int tm = 0; tm < 4; ++tm)
#pragma unroll
    for (int tn = 0; tn < 4; ++tn) {
      f32x4 s = __builtin_amdgcn_mfma_f32_16x16x32_bf16(
          qf[tm], kf[tn], (f32x4){0.f, 0.f, 0.f, 0.f}, 0, 0, 0);
      const int m = tn * 16 + l15;
#pragma unroll
      for (int r = 0; r < 4; ++r) {
        const int n = tm * 16 + quad * 4 + r;
        const float rad = dmv[tn] - dn[tm * 4 + r];
        float s1, c1;
        __sincosf(3.14159265358979323846f * rad, &s1, &c1);
        const float c2 = c1 * c1 - s1 * s1, t2 = 2.f * s1 * c1;
        const float c3 = c2 * c1 - t2 * s1, t3 = t2 * c1 + c2 * s1;
        const float c4 = c2 * c2 - t2 * t2, t4 = 2.f * t2 * c2;
        const float arv = ar0 + c1 * arc[0] + s1 * brc[0] + c2 * arc[1] +
                          t2 * brc[1] + c3 * arc[2] + t3 * brc[2] +
                          c4 * arc[3] + t4 * brc[3];
        float val = s[r] * SCALE + aphi[h * 4096 + n * 64 + m] + arv;
        if (rq[tm * 4 + r] != rk[tn]) val -= 100.f;
        S[tm][tn][r] = val;
      }
    }

#pragma unroll
  for (int tm = 0; tm < 4; ++tm)
#pragma unroll
    for (int r = 0; r < 4; ++r) {
      float mx = fmaxf(fmaxf(S[tm][0][r], S[tm][1][r]),
                       fmaxf(S[tm][2][r], S[tm][3][r]));
#pragma unroll
      for (int off = 1; off < 16; off <<= 1) mx = fmaxf(mx, __shfl_xor(mx, off));
      float sm = 0.f;
#pragma unroll
      for (int tn = 0; tn < 4; ++tn) {
        const float e = __expf(S[tm][tn][r] - mx);
        S[tm][tn][r] = e;
        sm += e;
      }
#pragma unroll
      for (int off = 1; off < 16; off <<= 1) sm += __shfl_xor(sm, off);
      const float inv = 1.0f / sm;
      const int n = tm * 16 + quad * 4 + r;
#pragma unroll
      for (int tn = 0; tn < 4; ++tn)
        sP[n * 72 + tn * 16 + l15] = f2bf(S[tm][tn][r] * inv);
    }
  __syncthreads();

  short8 vf[2][2];
#pragma unroll
  for (int ks = 0; ks < 2; ++ks)
#pragma unroll
    for (int td = 0; td < 2; ++td)
      vf[ks][td] =
          *(const short8*)&sVt[(td * 16 + l15) * 72 + ks * 32 + quad * 8];
  f32x4 O[4][2];
#pragma unroll
  for (int tm = 0; tm < 4; ++tm)
#pragma unroll
    for (int td = 0; td < 2; ++td) O[tm][td] = (f32x4){0.f, 0.f, 0.f, 0.f};
#pragma unroll
  for (int tm = 0; tm < 4; ++tm)
#pragma unroll
    for (int ks = 0; ks < 2; ++ks) {
      const short8 pf =
          *(const short8*)&sP[(tm * 16 + l15) * 72 + ks * 32 + quad * 8];
#pragma unroll
      for (int td = 0; td < 2; ++td)
        O[tm][td] =
            __builtin_amdgcn_mfma_f32_16x16x32_bf16(pf, vf[ks][td], O[tm][td], 0, 0, 0);
    }

#pragma unroll
  for (int tm = 0; tm < 4; ++tm)
#pragma unroll
    for (int td = 0; td < 2; ++td)
#pragma unroll
      for (int r = 0; r < 4; ++r) {
        const int n = tm * 16 + quad * 4 + r;
        const int d = td * 16 + l15;
        outp[(size_t)(w * 64 + n) * 512 + h * 32 + d] = f2bf(O[tm][td][r]);
      }
}

// ---------------------------------------------------------------------------
// Host
// ---------------------------------------------------------------------------
extern "C" void kernel_launch(void* const* d_in, const int* in_sizes, int n_in,
                              void* d_out, int out_size, void* d_ws,
                              size_t ws_size, hipStream_t stream) {
  const float* x = (const float*)d_in[0];
  const float* D = (const float*)d_in[1];
  const float* gamma1 = (const float*)d_in[2];
  const float* beta1 = (const float*)d_in[3];
  const float* Wqkv = (const float*)d_in[4];
  const float* bqkv = (const float*)d_in[5];
  const float* Wproj = (const float*)d_in[6];
  const float* bproj = (const float*)d_in[7];
  const float* a_p = (const float*)d_in[8];
  const float* b_p = (const float*)d_in[9];
  const float* a_r = (const float*)d_in[10];
  const float* b_r = (const float*)d_in[11];
  const float* gamma2 = (const float*)d_in[12];
  const float* beta2 = (const float*)d_in[13];
  const float* W1 = (const float*)d_in[14];
  const float* b1 = (const float*)d_in[15];
  const float* W2 = (const float*)d_in[16];
  const float* b2 = (const float*)d_in[17];
  float* out = (float*)d_out;

  char* ws = (char*)d_ws;
  const size_t OFF_XW = 0;                    // 67,108,864   (xw, later h2)
  const size_t OFF_QKV = 67108864;            // 268,435,456  (qkv, later g)
  const size_t OFF_AO = 335544320;            // 67,108,864   (attn out)
  const size_t OFF_WQT = 402653184;           // 1,572,864
  const size_t OFF_WPT = 404226048;           // 524,288
  const size_t OFF_W1T = 404750336;           // 2,097,152
  const size_t OFF_W2T = 406847488;           // 2,097,152
  const size_t OFF_APHI = 408944640;          // 262,144
  const size_t OFF_DW = 409206784;            // 262,144
  const size_t TOTAL = 409468928;
  if (ws_size < TOTAL) return;

  u16* xw = (u16*)(ws + OFF_XW);
  u16* qkv = (u16*)(ws + OFF_QKV);
  u16* ao = (u16*)(ws + OFF_AO);
  u16* WqkvT = (u16*)(ws + OFF_WQT);
  u16* WprojT = (u16*)(ws + OFF_WPT);
  u16* W1T = (u16*)(ws + OFF_W1T);
  u16* W2T = (u16*)(ws + OFF_W2T);
  float* aphiW = (float*)(ws + OFF_APHI);
  float* dwW = (float*)(ws + OFF_DW);
  u16* h2 = xw;   // reuse
  u16* gbuf = qkv;  // reuse

  wt_convert<<<dim3(48, 16), 256, 0, stream>>>(Wqkv, WqkvT, 512, 1536);
  wt_convert<<<dim3(16, 16), 256, 0, stream>>>(Wproj, WprojT, 512, 512);
  wt_convert<<<dim3(64, 16), 256, 0, stream>>>(W1, W1T, 512, 2048);
  wt_convert<<<dim3(16, 64), 256, 0, stream>>>(W2, W2T, 2048, 512);
  aphi_kernel<<<256, 256, 0, stream>>>(a_p, b_p, aphiW);
  ln1_win<<<65536, 64, 0, stream>>>(x, D, gamma1, beta1, xw, dwW);

  gemm_bt<0, 12><<<12 * 512, 256, 0, stream>>>(xw, WqkvT, bqkv, qkv, nullptr,
                                               nullptr, 65536, 1536, 512);
  attn_kernel<<<16384, 64, 0, stream>>>(qkv, dwW, aphiW, a_r, b_r, ao);
  gemm_bt<2, 4><<<4 * 512, 256, 0, stream>>>(ao, WprojT, bproj, nullptr, out,
                                             x, 65536, 512, 512);
  ln2_kernel<<<65536, 64, 0, stream>>>(out, gamma2, beta2, h2);
  gemm_bt<1, 16><<<16 * 512, 256, 0, stream>>>(h2, W1T, b1, gbuf, nullptr,
                                               nullptr, 65536, 2048, 512);
  gemm_bt<3, 4><<<4 * 512, 256, 0, stream>>>(gbuf, W2T, b2, nullptr, out,
                                             nullptr, 65536, 512, 2048);
}

// Round 3
// 1073.023 us; speedup vs baseline: 1.0582x; 1.0381x over previous
//
#include <hip/hip_runtime.h>
#include <hip/hip_bf16.h>
#include <cstdint>

// Problem constants
// B=16, H=W=64, C=512, NH=16, WS=8, SS=4, P=4, HID=2048, N=64, HD=32
// Bw = 1024 windows, tokens = 65536

typedef __attribute__((ext_vector_type(8))) short short8;
typedef __attribute__((ext_vector_type(4))) float f32x4;
typedef unsigned short u16;

__device__ __forceinline__ u16 f2bf(float f) {
  __hip_bfloat16 h = __float2bfloat16(f);
  return *reinterpret_cast<u16*>(&h);
}

__device__ __forceinline__ void gld_lds16(const u16* g, u16* l) {
  __builtin_amdgcn_global_load_lds(
      (const __attribute__((address_space(1))) void*)g,
      (__attribute__((address_space(3))) void*)l, 16, 0, 0);
}

// ---------------------------------------------------------------------------
// Weight convert + transpose: W [K,N] fp32 -> Wt [N,K] bf16
// ---------------------------------------------------------------------------
__global__ void wt_convert(const float* __restrict__ W, u16* __restrict__ Wt,
                           int K, int N) {
  __shared__ float tile[32][33];
  const int n0 = blockIdx.x * 32, k0 = blockIdx.y * 32;
  const int tx = threadIdx.x & 31, ty = threadIdx.x >> 5;  // 32 x 8
#pragma unroll
  for (int r = ty; r < 32; r += 8)
    tile[r][tx] = W[(size_t)(k0 + r) * N + n0 + tx];
  __syncthreads();
#pragma unroll
  for (int r = ty; r < 32; r += 8)
    Wt[(size_t)(n0 + r) * K + k0 + tx] = f2bf(tile[tx][r]);
}

// ---------------------------------------------------------------------------
// A_phi precompute: [NH=16][n=64][m=64] fp32
// ---------------------------------------------------------------------------
__global__ void aphi_kernel(const float* __restrict__ a_p,
                            const float* __restrict__ b_p,
                            float* __restrict__ aphi) {
  const int idx = blockIdx.x * 256 + threadIdx.x;  // 65536 total
  const int h = idx >> 12, n = (idx >> 6) & 63, m = idx & 63;
  const float ang = (float)((n & 7) - (m & 7)) * 0.09817477042468103f;  // 2pi/64
  float v = a_p[h];
#pragma unroll
  for (int p = 0; p < 4; ++p) {
    float s, c;
    __sincosf((float)(p + 1) * ang, &s, &c);
    v += (c * a_p[(p + 1) * 16 + h] + s * b_p[p * 16 + h]) * 0.25f;
  }
  aphi[idx] = v;
}

// ---------------------------------------------------------------------------
// LN1 + roll(-4,-4) + window partition -> xw bf16 [65536,512], dw fp32 [65536]
// one wave per output row
// ---------------------------------------------------------------------------
__global__ __launch_bounds__(64) void ln1_win(
    const float* __restrict__ x, const float* __restrict__ D,
    const float* __restrict__ gamma, const float* __restrict__ beta,
    u16* __restrict__ xw, float* __restrict__ dwout) {
  const int r = blockIdx.x;
  const int lane = threadIdx.x;
  const int w = r >> 6, n = r & 63;
  const int bb = w >> 6, nw = w & 63;
  const int wh = nw >> 3, ww = nw & 7;
  const int i = n >> 3, j = n & 7;
  const int sh = (wh * 8 + i + 4) & 63;
  const int sw = (ww * 8 + j + 4) & 63;
  const size_t src = ((size_t)bb * 4096 + sh * 64 + sw) * 512;
  float4 v0 = *(const float4*)(x + src + lane * 8);
  float4 v1 = *(const float4*)(x + src + lane * 8 + 4);
  float vv[8] = {v0.x, v0.y, v0.z, v0.w, v1.x, v1.y, v1.z, v1.w};
  float s = 0.f, s2 = 0.f;
#pragma unroll
  for (int e = 0; e < 8; ++e) { s += vv[e]; s2 += vv[e] * vv[e]; }
#pragma unroll
  for (int off = 32; off > 0; off >>= 1) {
    s += __shfl_xor(s, off);
    s2 += __shfl_xor(s2, off);
  }
  const float mean = s * (1.0f / 512.0f);
  const float var = s2 * (1.0f / 512.0f) - mean * mean;
  const float rstd = rsqrtf(var + 1e-5f);
  const int c0 = lane * 8;
  u16 ob[8];
#pragma unroll
  for (int e = 0; e < 8; ++e)
    ob[e] = f2bf((vv[e] - mean) * rstd * gamma[c0 + e] + beta[c0 + e]);
  *(short8*)(xw + (size_t)r * 512 + c0) = *(short8*)ob;
  if (lane == 0) dwout[r] = D[(size_t)bb * 4096 + sh * 64 + sw];
}

// ---------------------------------------------------------------------------
// LN2 (token order): x2 fp32 -> h2 bf16
// ---------------------------------------------------------------------------
__global__ __launch_bounds__(64) void ln2_kernel(
    const float* __restrict__ xin, const float* __restrict__ gamma,
    const float* __restrict__ beta, u16* __restrict__ h2) {
  const int r = blockIdx.x;
  const int lane = threadIdx.x;
  const size_t src = (size_t)r * 512;
  float4 v0 = *(const float4*)(xin + src + lane * 8);
  float4 v1 = *(const float4*)(xin + src + lane * 8 + 4);
  float vv[8] = {v0.x, v0.y, v0.z, v0.w, v1.x, v1.y, v1.z, v1.w};
  float s = 0.f, s2 = 0.f;
#pragma unroll
  for (int e = 0; e < 8; ++e) { s += vv[e]; s2 += vv[e] * vv[e]; }
#pragma unroll
  for (int off = 32; off > 0; off >>= 1) {
    s += __shfl_xor(s, off);
    s2 += __shfl_xor(s2, off);
  }
  const float mean = s * (1.0f / 512.0f);
  const float var = s2 * (1.0f / 512.0f) - mean * mean;
  const float rstd = rsqrtf(var + 1e-5f);
  const int c0 = lane * 8;
  u16 ob[8];
#pragma unroll
  for (int e = 0; e < 8; ++e)
    ob[e] = f2bf((vv[e] - mean) * rstd * gamma[c0 + e] + beta[c0 + e]);
  *(short8*)(h2 + src + c0) = *(short8*)ob;
}

// ---------------------------------------------------------------------------
// bf16 GEMM, C[M,N] = A[M,K] * Bt[N,K]^T (+bias, +epilogue)
// 256x128 tile, BK=32, 512 threads = 8 waves (4x2), 16x16x32 mfma.
// 85 FLOP per staged byte (vs 64 at 128x128) -> staging no longer L2-BW cap.
// global_load_lds width-16 staging, XOR chunk swizzle (2-way/free banks).
// 1D grid + XCD swizzle: lid&7 stripes M across XCDs for A-tile L2 locality.
// EPI: 0 = bias->bf16; 1 = bias+gelu->bf16;
//      2 = bias + unwindow/unroll + residual(x) -> fp32 d_out;
//      3 = bias + accumulate into fp32 d_out (token order)
// ---------------------------------------------------------------------------
template <int EPI, int GX>
__global__ __launch_bounds__(512, 4) void gemm_bt(
    const u16* __restrict__ A, const u16* __restrict__ Bt,
    const float* __restrict__ bias, u16* __restrict__ outb,
    float* __restrict__ outf, const float* __restrict__ addsrc,
    int M, int N, int K) {
  __shared__ __align__(16) u16 sA[256 * 32];
  __shared__ __align__(16) u16 sB[128 * 32];
  const int t = threadIdx.x;
  // XCD-locality swizzle: stripe M across XCDs, iterate N fast within XCD.
  const int lid = blockIdx.x;
  const int xcd = lid & 7;
  const int tt = lid >> 3;
  const int bx = tt % GX;
  const int by = (tt / GX) * 8 + xcd;
  const int m0 = by * 256, n0 = bx * 128;
  const int lane = t & 63, wave = t >> 6;
  const int wm = wave >> 1, wn = wave & 1;  // 4 x 2 wave grid
  const int l15 = lane & 15, quad = lane >> 4;

  f32x4 acc[4][4];
#pragma unroll
  for (int i = 0; i < 4; ++i)
#pragma unroll
    for (int j = 0; j < 4; ++j) acc[i][j] = (f32x4){0.f, 0.f, 0.f, 0.f};

  // staging map: flat 16B slot s -> row = s>>2, physchunk = s&3,
  // logical chunk = physchunk ^ ((row>>1)&3)  (bank swizzle folded to global)
  const int sa0 = t, sa1 = t + 512, sb0 = t;  // A: 1024 slots, B: 512 slots
  const int ra0 = sa0 >> 2, pa0 = sa0 & 3, la0 = pa0 ^ ((ra0 >> 1) & 3);
  const int ra1 = sa1 >> 2, pa1 = sa1 & 3, la1 = pa1 ^ ((ra1 >> 1) & 3);
  const int rb0 = sb0 >> 2, pb0 = sb0 & 3, lb0c = pb0 ^ ((rb0 >> 1) & 3);
  const u16* Ag0 = A + (size_t)(m0 + ra0) * K + la0 * 8;
  const u16* Ag1 = A + (size_t)(m0 + ra1) * K + la1 * 8;
  const u16* Bg0 = Bt + (size_t)(n0 + rb0) * K + lb0c * 8;
  u16* lA0 = &sA[sa0 * 8];
  u16* lA1 = &sA[sa1 * 8];
  u16* lB0 = &sB[sb0 * 8];

  for (int kk = 0; kk < K; kk += 32) {
    gld_lds16(Ag0 + kk, lA0);
    gld_lds16(Ag1 + kk, lA1);
    gld_lds16(Bg0 + kk, lB0);
    __syncthreads();
    short8 af[4], bf[4];
#pragma unroll
    for (int i = 0; i < 4; ++i) {
      const int ra = wm * 64 + i * 16 + l15;
      const int ca = quad ^ ((ra >> 1) & 3);
      af[i] = *(const short8*)&sA[ra * 32 + ca * 8];
      const int rb = wn * 64 + i * 16 + l15;
      const int cb = quad ^ ((rb >> 1) & 3);
      bf[i] = *(const short8*)&sB[rb * 32 + cb * 8];
    }
#pragma unroll
    for (int i = 0; i < 4; ++i)
#pragma unroll
      for (int j = 0; j < 4; ++j)
        acc[i][j] = __builtin_amdgcn_mfma_f32_16x16x32_bf16(af[i], bf[j],
                                                            acc[i][j], 0, 0, 0);
    __syncthreads();
  }

#pragma unroll
  for (int i = 0; i < 4; ++i) {
    const int gr0 = m0 + wm * 64 + i * 16 + quad * 4;
#pragma unroll
    for (int j = 0; j < 4; ++j) {
      const int gc = n0 + wn * 64 + j * 16 + l15;
      const float bv = bias[gc];
      f32x4 a = acc[i][j];
#pragma unroll
      for (int r = 0; r < 4; ++r) {
        const int gr = gr0 + r;
        float val = a[r] + bv;
        if (EPI == 0) {
          outb[(size_t)gr * N + gc] = f2bf(val);
        } else if (EPI == 1) {
          val = 0.5f * val * (1.0f + erff(val * 0.7071067811865475f));
          outb[(size_t)gr * N + gc] = f2bf(val);
        } else if (EPI == 2) {
          const int w = gr >> 6, n = gr & 63;
          const int bb = w >> 6, nw = w & 63;
          const int wh = nw >> 3, ww = nw & 7;
          const int ii = n >> 3, jj = n & 7;
          const int th = (wh * 8 + ii + 4) & 63;
          const int tw = (ww * 8 + jj + 4) & 63;
          const size_t tok = (size_t)bb * 4096 + th * 64 + tw;
          outf[tok * 512 + gc] = addsrc[tok * 512 + gc] + val;
        } else {
          outf[(size_t)gr * N + gc] += val;
        }
      }
    }
  }
}

// ---------------------------------------------------------------------------
// Fused windowed attention, one wave per (window, head).
// S = QK^T*scale + A_phi + A_r(trig recurrence) + shift-mask; in-register
// softmax (16-lane shuffles); P -> LDS -> A-frag; O = P V via mfma.
// ---------------------------------------------------------------------------
__device__ __forceinline__ int bandf(int p) {
  return p < 56 ? 0 : (p < 60 ? 1 : 2);
}

__global__ void attn_kernel(const u16* __restrict__ qkv,
                            const float* __restrict__ dw,
                            const float* __restrict__ aphi,
                            const float* __restrict__ a_r,
                            const float* __restrict__ b_r,
                            u16* __restrict__ outp) {
  __shared__ __align__(16) u16 sVt[32 * 72];
  __shared__ __align__(16) u16 sP[64 * 72];
  __shared__ float sdw[64];
  const int bid = blockIdx.x;
  const int w = bid >> 4, h = bid & 15;
  const int lane = threadIdx.x;
  const int l15 = lane & 15, quad = lane >> 4;
  const int nw = w & 63, wh = nw >> 3, wwc = nw & 7;

  const float ar0 = a_r[h];
  float arc[4], brc[4];
#pragma unroll
  for (int p = 0; p < 4; ++p) {
    arc[p] = a_r[(p + 1) * 16 + h] * 0.25f;
    brc[p] = b_r[p * 16 + h] * 0.25f;
  }

  sdw[lane] = dw[w * 64 + lane];
  {
    const u16* vrow = qkv + (size_t)(w * 64 + lane) * 1536 + 1024 + h * 32;
    u16 vt[32];
#pragma unroll
    for (int c = 0; c < 4; ++c)
      *(short8*)&vt[c * 8] = *(const short8*)(vrow + c * 8);
#pragma unroll
    for (int d = 0; d < 32; ++d) sVt[d * 72 + lane] = vt[d];
  }
  __syncthreads();

  short8 qf[4], kf[4];
#pragma unroll
  for (int tq = 0; tq < 4; ++tq) {
    qf[tq] = *(const short8*)(qkv + (size_t)(w * 64 + tq * 16 + l15) * 1536 +
                              h * 32 + quad * 8);
    kf[tq] = *(const short8*)(qkv + (size_t)(w * 64 + tq * 16 + l15) * 1536 +
                              512 + h * 32 + quad * 8);
  }

  float dn[16];
  int rq[16];
#pragma unroll
  for (int tm = 0; tm < 4; ++tm)
#pragma unroll
    for (int r = 0; r < 4; ++r) {
      const int n = tm * 16 + quad * 4 + r;
      dn[tm * 4 + r] = sdw[n];
      rq[tm * 4 + r] = bandf(wh * 8 + (n >> 3)) * 4 + bandf(wwc * 8 + (n & 7));
    }
  float dmv[4];
  int rk[4];
#pragma unroll
  for (int tn = 0; tn < 4; ++tn) {
    const int m = tn * 16 + l15;
    dmv[tn] = sdw[m];
    rk[tn] = bandf(wh * 8 + (m >> 3)) * 4 + bandf(wwc * 8 + (m & 7));
  }

  f32x4 S[4][4];
  const float SCALE = 0.17677669529663687f;  // 32^-0.5
#pragma unroll
  for (int tm = 0; tm < 4; ++tm)
#pragma unroll
    for (int tn = 0; tn < 4; ++tn) {
      f32x4 s = __builtin_amdgcn_mfma_f32_16x16x32_bf16(
          qf[tm], kf[tn], (f32x4){0.f, 0.f, 0.f, 0.f}, 0, 0, 0);
      const int m = tn * 16 + l15;
#pragma unroll
      for (int r = 0; r < 4; ++r) {
        const int n = tm * 16 + quad * 4 + r;
        const float rad = dmv[tn] - dn[tm * 4 + r];
        float s1, c1;
        __sincosf(3.14159265358979323846f * rad, &s1, &c1);
        const float c2 = c1 * c1 - s1 * s1, t2 = 2.f * s1 * c1;
        const float c3 = c2 * c1 - t2 * s1, t3 = t2 * c1 + c2 * s1;
        const float c4 = c2 * c2 - t2 * t2, t4 = 2.f * t2 * c2;
        const float arv = ar0 + c1 * arc[0] + s1 * brc[0] + c2 * arc[1] +
                          t2 * brc[1] + c3 * arc[2] + t3 * brc[2] +
                          c4 * arc[3] + t4 * brc[3];
        float val = s[r] * SCALE + aphi[h * 4096 + n * 64 + m] + arv;
        if (rq[tm * 4 + r] != rk[tn]) val -= 100.f;
        S[tm][tn][r] = val;
      }
    }

#pragma unroll
  for (int tm = 0; tm < 4; ++tm)
#pragma unroll
    for (int r = 0; r < 4; ++r) {
      float mx = fmaxf(fmaxf(S[tm][0][r], S[tm][1][r]),
                       fmaxf(S[tm][2][r], S[tm][3][r]));
#pragma unroll
      for (int off = 1; off < 16; off <<= 1) mx = fmaxf(mx, __shfl_xor(mx, off));
      float sm = 0.f;
#pragma unroll
      for (int tn = 0; tn < 4; ++tn) {
        const float e = __expf(S[tm][tn][r] - mx);
        S[tm][tn][r] = e;
        sm += e;
      }
#pragma unroll
      for (int off = 1; off < 16; off <<= 1) sm += __shfl_xor(sm, off);
      const float inv = 1.0f / sm;
      const int n = tm * 16 + quad * 4 + r;
#pragma unroll
      for (int tn = 0; tn < 4; ++tn)
        sP[n * 72 + tn * 16 + l15] = f2bf(S[tm][tn][r] * inv);
    }
  __syncthreads();

  short8 vf[2][2];
#pragma unroll
  for (int ks = 0; ks < 2; ++ks)
#pragma unroll
    for (int td = 0; td < 2; ++td)
      vf[ks][td] =
          *(const short8*)&sVt[(td * 16 + l15) * 72 + ks * 32 + quad * 8];
  f32x4 O[4][2];
#pragma unroll
  for (int tm = 0; tm < 4; ++tm)
#pragma unroll
    for (int td = 0; td < 2; ++td) O[tm][td] = (f32x4){0.f, 0.f, 0.f, 0.f};
#pragma unroll
  for (int tm = 0; tm < 4; ++tm)
#pragma unroll
    for (int ks = 0; ks < 2; ++ks) {
      const short8 pf =
          *(const short8*)&sP[(tm * 16 + l15) * 72 + ks * 32 + quad * 8];
#pragma unroll
      for (int td = 0; td < 2; ++td)
        O[tm][td] =
            __builtin_amdgcn_mfma_f32_16x16x32_bf16(pf, vf[ks][td], O[tm][td], 0, 0, 0);
    }

#pragma unroll
  for (int tm = 0; tm < 4; ++tm)
#pragma unroll
    for (int td = 0; td < 2; ++td)
#pragma unroll
      for (int r = 0; r < 4; ++r) {
        const int n = tm * 16 + quad * 4 + r;
        const int d = td * 16 + l15;
        outp[(size_t)(w * 64 + n) * 512 + h * 32 + d] = f2bf(O[tm][td][r]);
      }
}

// ---------------------------------------------------------------------------
// Host
// ---------------------------------------------------------------------------
extern "C" void kernel_launch(void* const* d_in, const int* in_sizes, int n_in,
                              void* d_out, int out_size, void* d_ws,
                              size_t ws_size, hipStream_t stream) {
  const float* x = (const float*)d_in[0];
  const float* D = (const float*)d_in[1];
  const float* gamma1 = (const float*)d_in[2];
  const float* beta1 = (const float*)d_in[3];
  const float* Wqkv = (const float*)d_in[4];
  const float* bqkv = (const float*)d_in[5];
  const float* Wproj = (const float*)d_in[6];
  const float* bproj = (const float*)d_in[7];
  const float* a_p = (const float*)d_in[8];
  const float* b_p = (const float*)d_in[9];
  const float* a_r = (const float*)d_in[10];
  const float* b_r = (const float*)d_in[11];
  const float* gamma2 = (const float*)d_in[12];
  const float* beta2 = (const float*)d_in[13];
  const float* W1 = (const float*)d_in[14];
  const float* b1 = (const float*)d_in[15];
  const float* W2 = (const float*)d_in[16];
  const float* b2 = (const float*)d_in[17];
  float* out = (float*)d_out;

  char* ws = (char*)d_ws;
  const size_t OFF_XW = 0;                    // 67,108,864   (xw, later h2)
  const size_t OFF_QKV = 67108864;            // 268,435,456  (qkv, later g)
  const size_t OFF_AO = 335544320;            // 67,108,864   (attn out)
  const size_t OFF_WQT = 402653184;           // 1,572,864
  const size_t OFF_WPT = 404226048;           // 524,288
  const size_t OFF_W1T = 404750336;           // 2,097,152
  const size_t OFF_W2T = 406847488;           // 2,097,152
  const size_t OFF_APHI = 408944640;          // 262,144
  const size_t OFF_DW = 409206784;            // 262,144
  const size_t TOTAL = 409468928;
  if (ws_size < TOTAL) return;

  u16* xw = (u16*)(ws + OFF_XW);
  u16* qkv = (u16*)(ws + OFF_QKV);
  u16* ao = (u16*)(ws + OFF_AO);
  u16* WqkvT = (u16*)(ws + OFF_WQT);
  u16* WprojT = (u16*)(ws + OFF_WPT);
  u16* W1T = (u16*)(ws + OFF_W1T);
  u16* W2T = (u16*)(ws + OFF_W2T);
  float* aphiW = (float*)(ws + OFF_APHI);
  float* dwW = (float*)(ws + OFF_DW);
  u16* h2 = xw;   // reuse
  u16* gbuf = qkv;  // reuse

  wt_convert<<<dim3(48, 16), 256, 0, stream>>>(Wqkv, WqkvT, 512, 1536);
  wt_convert<<<dim3(16, 16), 256, 0, stream>>>(Wproj, WprojT, 512, 512);
  wt_convert<<<dim3(64, 16), 256, 0, stream>>>(W1, W1T, 512, 2048);
  wt_convert<<<dim3(16, 64), 256, 0, stream>>>(W2, W2T, 2048, 512);
  aphi_kernel<<<256, 256, 0, stream>>>(a_p, b_p, aphiW);
  ln1_win<<<65536, 64, 0, stream>>>(x, D, gamma1, beta1, xw, dwW);

  // 256-row M-tiles: 65536/256 = 256 by-tiles
  gemm_bt<0, 12><<<12 * 256, 512, 0, stream>>>(xw, WqkvT, bqkv, qkv, nullptr,
                                               nullptr, 65536, 1536, 512);
  attn_kernel<<<16384, 64, 0, stream>>>(qkv, dwW, aphiW, a_r, b_r, ao);
  gemm_bt<2, 4><<<4 * 256, 512, 0, stream>>>(ao, WprojT, bproj, nullptr, out,
                                             x, 65536, 512, 512);
  ln2_kernel<<<65536, 64, 0, stream>>>(out, gamma2, beta2, h2);
  gemm_bt<1, 16><<<16 * 256, 512, 0, stream>>>(h2, W1T, b1, gbuf, nullptr,
                                               nullptr, 65536, 2048, 512);
  gemm_bt<3, 4><<<4 * 256, 512, 0, stream>>>(gbuf, W2T, b2, nullptr, out,
                                             nullptr, 65536, 512, 2048);
}